// Round 4
// baseline (716.411 us; speedup 1.0000x reference)
//
#include <hip/hip_runtime.h>
#include <cstdint>
#include <cstddef>

// QuantLlamaAttention: int8 fake-quant Llama attention block, MI355X (gfx950).
// All matmuls carry quantized INTEGER values in _Float16 (exact for |v|<=2048)
// through f16 MFMA, fp32 accumulate, scales applied in epilogue.
// softmax prob amax is exactly 1.0 (causal row 0) -> static prob scale 1/127,
// enabling a two-pass flash attention with exact quantization (no S matrix).
//
// R1: same-address atomicMax serialization -> block partials / 1 atomic per block.
// R2: expf->__expf, diag-only masking, q-tile pairing, m97-style GEMM staging.
// R3: k_attn was LDS-pipe-bound (conflicts 1.78e7, ~80% LDS cycles). Redesign:
//     compute S^T = K.Q^T so the QK C-layout (col=q, row=kpos) IS the PV
//     B-operand layout of mfma_f32_16x16x16f16 -> P never touches LDS.
//     2-head GQA fusion shares sK/sV frags; double-buffered staging gives
//     1 barrier/tile; V-frags as b64 (conflict-free); coalesced AO stores.

#define S_LEN   2048
#define HDIM    4096
#define NHEADS  32
#define NKVH    8
#define HEADD   128
#define QMAXF   127.0f
#define ROPE_BLOCKS 20480

typedef _Float16 half8  __attribute__((ext_vector_type(8)));
typedef _Float16 half4  __attribute__((ext_vector_type(4)));
typedef float    floatx4 __attribute__((ext_vector_type(4)));

// ---------------- helpers ----------------
__device__ __forceinline__ float wave_max64(float v){
#pragma unroll
  for (int off = 32; off > 0; off >>= 1) v = fmaxf(v, __shfl_xor(v, off));
  return v;
}
__device__ __forceinline__ void atomic_max_f(unsigned* p, float v){
  atomicMax(p, __float_as_uint(v));   // v >= 0: uint bits order-preserving
}
__device__ __forceinline__ float q8(float x, float scale){
  return fminf(fmaxf(rintf(x / scale), -128.f), 127.f);  // rintf = half-even, matches jnp.round
}
// async global->LDS, 16B per lane. HW: LDS dest = wave-uniform base + lane*16.
__device__ __forceinline__ void gload_lds16(const _Float16* g, _Float16* l){
  __builtin_amdgcn_global_load_lds((const __attribute__((address_space(1))) void*)g,
                                   (__attribute__((address_space(3))) void*)l, 16, 0, 0);
}

// block-level max of per-wave maxima (256 threads = 4 waves), then ONE atomic
__device__ __forceinline__ void block_atomic_max(float m, unsigned* out){
  m = wave_max64(m);
  __shared__ float red[4];
  int wid = threadIdx.x >> 6;
  if ((threadIdx.x & 63) == 0) red[wid] = m;
  __syncthreads();
  if (threadIdx.x == 0)
    atomic_max_f(out, fmaxf(fmaxf(red[0], red[1]), fmaxf(red[2], red[3])));
}

// ---------------- tiny kernels ----------------
__global__ void k_init(float* scal){ if (threadIdx.x < 16) scal[threadIdx.x] = 0.0f; }

__global__ void k_amax(const float* __restrict__ x, size_t n4, unsigned* __restrict__ out){
  size_t i = (size_t)blockIdx.x * blockDim.x + threadIdx.x;
  size_t stride = (size_t)gridDim.x * blockDim.x;
  float m = 0.f;
  for (; i < n4; i += stride){
    float4 v = ((const float4*)x)[i];
    m = fmaxf(m, fmaxf(fmaxf(fabsf(v.x), fabsf(v.y)), fmaxf(fabsf(v.z), fabsf(v.w))));
  }
  block_atomic_max(m, out);
}

// amax over the V slice (cols [5120,6144)) of Y[2048][6144]
__global__ void k_amax_v(const float* __restrict__ Y, unsigned* __restrict__ out){
  size_t i = (size_t)blockIdx.x * blockDim.x + threadIdx.x;
  size_t stride = (size_t)gridDim.x * blockDim.x;
  float m = 0.f;
  for (size_t e = i; e < (size_t)S_LEN * 1024; e += stride){
    size_t s = e >> 10; int c = (int)(e & 1023);
    m = fmaxf(m, fabsf(Y[s * 6144 + 5120 + c]));
  }
  block_atomic_max(m, out);
}

// per-tensor quantize fp32 -> integer-valued f16
__global__ void k_quant(const float* __restrict__ x, _Float16* __restrict__ q,
                        size_t n4, const float* __restrict__ amax){
  float scale = fmaxf(*amax, 1e-8f) / QMAXF;
  size_t i = (size_t)blockIdx.x * blockDim.x + threadIdx.x;
  size_t stride = (size_t)gridDim.x * blockDim.x;
  for (; i < n4; i += stride){
    float4 v = ((const float4*)x)[i];
    union { _Float16 h[4]; uint2 u; } pk;
    pk.h[0] = (_Float16)q8(v.x, scale);
    pk.h[1] = (_Float16)q8(v.y, scale);
    pk.h[2] = (_Float16)q8(v.z, scale);
    pk.h[3] = (_Float16)q8(v.w, scale);
    ((uint2*)q)[i] = pk.u;
  }
}

// per-row weight quantization: rows 0..6143 -> Wall (wq|wk|wv), 6144..10239 -> Wo
__global__ __launch_bounds__(256) void k_quant_w(
    const float* __restrict__ wq, const float* __restrict__ wk,
    const float* __restrict__ wv, const float* __restrict__ wo,
    _Float16* __restrict__ Wall, _Float16* __restrict__ Wo,
    float* __restrict__ wsc)
{
  int row = blockIdx.x;
  const float* src; _Float16* dst;
  if (row < 4096)      { src = wq + (size_t)row * HDIM;          dst = Wall + (size_t)row * HDIM; }
  else if (row < 5120) { src = wk + (size_t)(row - 4096) * HDIM; dst = Wall + (size_t)row * HDIM; }
  else if (row < 6144) { src = wv + (size_t)(row - 5120) * HDIM; dst = Wall + (size_t)row * HDIM; }
  else                 { src = wo + (size_t)(row - 6144) * HDIM; dst = Wo + (size_t)(row - 6144) * HDIM; }
  float4 v[4]; float m = 0.f;
#pragma unroll
  for (int i = 0; i < 4; i++){
    v[i] = ((const float4*)src)[threadIdx.x + i * 256];
    m = fmaxf(m, fmaxf(fmaxf(fabsf(v[i].x), fabsf(v[i].y)), fmaxf(fabsf(v[i].z), fabsf(v[i].w))));
  }
  m = wave_max64(m);
  __shared__ float red[4];
  int wid = threadIdx.x >> 6;
  if ((threadIdx.x & 63) == 0) red[wid] = m;
  __syncthreads();
  float am = fmaxf(fmaxf(red[0], red[1]), fmaxf(red[2], red[3]));
  float scale = fmaxf(am, 1e-8f) / QMAXF;
  if (threadIdx.x == 0) wsc[row] = scale;
#pragma unroll
  for (int i = 0; i < 4; i++){
    union { _Float16 h[4]; uint2 u; } pk;
    pk.h[0] = (_Float16)q8(v[i].x, scale);
    pk.h[1] = (_Float16)q8(v[i].y, scale);
    pk.h[2] = (_Float16)q8(v[i].z, scale);
    pk.h[3] = (_Float16)q8(v[i].w, scale);
    ((uint2*)dst)[threadIdx.x + i * 256] = pk.u;
  }
}

// RoPE in-place on Y (q: heads 0..31, k: heads 32..39) + per-block partials
__global__ __launch_bounds__(256) void k_rope(
    float* __restrict__ Y, const float* __restrict__ cosb,
    const float* __restrict__ sinb,
    float* __restrict__ qpart, float* __restrict__ kpart)
{
  int idx = blockIdx.x * 256 + threadIdx.x;   // 2048*40*64 total
  int s = idx / (40 * 64);
  int rem = idx - s * 40 * 64;
  int head = rem >> 6;        // wave-uniform (64 threads per head slot)
  int d = rem & 63;
  size_t base = (size_t)s * 6144 + (head < 32 ? head * 128 : 4096 + (head - 32) * 128);
  float x1 = Y[base + d], x2 = Y[base + d + 64];
  float c1 = cosb[s * 128 + d],      s1 = sinb[s * 128 + d];
  float c2 = cosb[s * 128 + d + 64], s2 = sinb[s * 128 + d + 64];
  float o1 = x1 * c1 - x2 * s1;
  float o2 = x2 * c2 + x1 * s2;
  Y[base + d] = o1; Y[base + d + 64] = o2;
  float m = wave_max64(fmaxf(fabsf(o1), fabsf(o2)));
  __shared__ float wmax[4]; __shared__ int wisq[4];
  int wid = threadIdx.x >> 6;
  if ((threadIdx.x & 63) == 0){ wmax[wid] = m; wisq[wid] = (head < 32); }
  __syncthreads();
  if (threadIdx.x == 0){
    float qm = 0.f, km = 0.f;
#pragma unroll
    for (int w = 0; w < 4; w++){
      if (wisq[w]) qm = fmaxf(qm, wmax[w]); else km = fmaxf(km, wmax[w]);
    }
    qpart[blockIdx.x] = qm; kpart[blockIdx.x] = km;
  }
}

// reduce rope partials: block 0 -> scal[1] (q), block 1 -> scal[2] (k)
__global__ __launch_bounds__(256) void k_reduce_qk(
    const float* __restrict__ qpart, const float* __restrict__ kpart,
    float* __restrict__ scal)
{
  const float* src = blockIdx.x ? kpart : qpart;
  float m = 0.f;
  for (int i = threadIdx.x; i < ROPE_BLOCKS; i += 256) m = fmaxf(m, src[i]);
  m = wave_max64(m);
  __shared__ float red[4];
  int wid = threadIdx.x >> 6;
  if ((threadIdx.x & 63) == 0) red[wid] = m;
  __syncthreads();
  if (threadIdx.x == 0)
    scal[1 + blockIdx.x] = fmaxf(fmaxf(red[0], red[1]), fmaxf(red[2], red[3]));
}

// quantize Q,K slices of Y (cols [0,5120)) -> Qh[2048][4096], Kh[2048][1024]
__global__ __launch_bounds__(256) void k_quant_qk(
    const float* __restrict__ Y, _Float16* __restrict__ Qh,
    _Float16* __restrict__ Kh, const float* __restrict__ scal)
{
  int i = blockIdx.x * 256 + threadIdx.x;       // 2048*5120/4 float4 units
  int s = i / 1280, c4 = i - s * 1280;
  int col = c4 * 4;
  float4 v = *(const float4*)(Y + (size_t)s * 6144 + col);
  float scale = fmaxf(col < 4096 ? scal[1] : scal[2], 1e-8f) / QMAXF;
  union { _Float16 h[4]; uint2 u; } pk;
  pk.h[0] = (_Float16)q8(v.x, scale);
  pk.h[1] = (_Float16)q8(v.y, scale);
  pk.h[2] = (_Float16)q8(v.z, scale);
  pk.h[3] = (_Float16)q8(v.w, scale);
  if (col < 4096) *(uint2*)(Qh + (size_t)s * 4096 + col) = pk.u;
  else            *(uint2*)(Kh + (size_t)s * 1024 + (col - 4096)) = pk.u;
}

// quantize V slice of Y with LDS-tiled transpose -> Vt[8][128][2048]
__global__ __launch_bounds__(256) void k_quant_vt(
    const float* __restrict__ Y, _Float16* __restrict__ Vt,
    const float* __restrict__ scal)
{
  __shared__ _Float16 sT[64][72];      // [d][s]
  const int s0 = blockIdx.x * 64, kvh = blockIdx.y, dh = blockIdx.z;
  const float scale = fmaxf(scal[3], 1e-8f) / QMAXF;
  const int d = threadIdx.x & 63, srow = threadIdx.x >> 6;
#pragma unroll
  for (int i = 0; i < 16; i++){
    int s = srow + i * 4;
    float v = Y[(size_t)(s0 + s) * 6144 + 5120 + kvh * 128 + dh * 64 + d];
    sT[d][s] = (_Float16)q8(v, scale);
  }
  __syncthreads();
  const int dr = threadIdx.x >> 2, j = threadIdx.x & 3;   // 64 d-rows x 4 lanes
  _Float16* dst = Vt + (size_t)kvh * HEADD * S_LEN + (size_t)(dh * 64 + dr) * S_LEN + s0 + j * 16;
  *(uint4*)(dst)     = *(const uint4*)(&sT[dr][j * 16]);
  *(uint4*)(dst + 8) = *(const uint4*)(&sT[dr][j * 16 + 8]);
}

// ---------------- GEMM: C[M][N] = (A[M][K] . B[N][K]^T) * sa * sb[n] ----------------
// m97 structure: unpadded [128][32] LDS, global_load_lds width=16, 2 barriers/iter
__global__ __launch_bounds__(256) void k_gemm_nt(
    const _Float16* __restrict__ A, const _Float16* __restrict__ B,
    const float* __restrict__ amax_a, const float* __restrict__ sb,
    float* __restrict__ C, int M, int N, int K)
{
  __shared__ _Float16 sA[128 * 32];
  __shared__ _Float16 sB[128 * 32];
  const int m0 = blockIdx.x * 128;
  const int n0 = blockIdx.y * 128;
  const int tid = threadIdx.x;
  const int w = tid >> 6, lane = tid & 63;
  const int quad = lane >> 4, l16 = lane & 15;
  const int wm = (w & 1) * 64, wn = (w >> 1) * 64;
  floatx4 acc[4][4] = {};
  const int srow = w * 16 + (lane >> 2);
  const int scol = (lane & 3) * 8;
  const _Float16* gA0 = A + (size_t)(m0 + srow) * K + scol;
  const _Float16* gA1 = A + (size_t)(m0 + 64 + srow) * K + scol;
  const _Float16* gB0 = B + (size_t)(n0 + srow) * K + scol;
  const _Float16* gB1 = B + (size_t)(n0 + 64 + srow) * K + scol;
  _Float16* dA0 = sA + w * 512 + lane * 8;
  _Float16* dA1 = sA + 2048 + w * 512 + lane * 8;
  _Float16* dB0 = sB + w * 512 + lane * 8;
  _Float16* dB1 = sB + 2048 + w * 512 + lane * 8;

  for (int k0 = 0; k0 < K; k0 += 32){
    __syncthreads();
    gload_lds16(gA0 + k0, dA0);
    gload_lds16(gA1 + k0, dA1);
    gload_lds16(gB0 + k0, dB0);
    gload_lds16(gB1 + k0, dB1);
    __syncthreads();
    half8 af[4], bf[4];
#pragma unroll
    for (int i = 0; i < 4; i++){
      af[i] = *(const half8*)(sA + (wm + i * 16 + l16) * 32 + quad * 8);
      bf[i] = *(const half8*)(sB + (wn + i * 16 + l16) * 32 + quad * 8);
    }
#pragma unroll
    for (int i = 0; i < 4; i++)
#pragma unroll
      for (int j = 0; j < 4; j++)
        acc[i][j] = __builtin_amdgcn_mfma_f32_16x16x32_f16(af[i], bf[j], acc[i][j], 0, 0, 0);
  }
  const float sa = fmaxf(*amax_a, 1e-8f) / QMAXF;
#pragma unroll
  for (int i = 0; i < 4; i++){
    int row = m0 + wm + i * 16 + quad * 4;
#pragma unroll
    for (int j = 0; j < 4; j++){
      int col = n0 + wn + j * 16 + l16;
      float sc2 = sa * sb[col];
#pragma unroll
      for (int rr = 0; rr < 4; rr++)
        C[(size_t)(row + rr) * N + col] = acc[i][j][rr] * sc2;
    }
  }
}

// ---------------- flash attention, S^T orientation, exact quantized softmax ----
// block = (q-tile pair (x, 31-x), head-pair). S^T = K.Q^T so QK's C-layout
// (col=q, row=kpos) is directly the PV B-operand of mfma_f32_16x16x16f16:
// P never goes through LDS. 2 heads share sK/sV frag reads. Double-buffered
// staging: one barrier per k-tile, prefetch held in registers.
__global__ __launch_bounds__(256, 2) void k_attn(
    const _Float16* __restrict__ Qh,  // [2048][4096]  (s, h*128+d) int-f16
    const _Float16* __restrict__ Kh,  // [2048][1024]  (s, kvh*128+d)
    const _Float16* __restrict__ Vt,  // [8][128][2048] (kvh, d, s)
    const float* __restrict__ scal,
    float* __restrict__ AO)           // [2048][4096] fp32
{
  const int h0  = blockIdx.y * 2;          // heads h0, h0+1 (same kv group)
  const int kvh = h0 >> 2;
  const int tid = threadIdx.x;
  const int wid = tid >> 6, lane = tid & 63;
  const int quad = lane >> 4, l16 = lane & 15;

  __shared__ _Float16 sK[2][64 * 136];     // [buf][kpos][d]  (+8 pad)
  __shared__ _Float16 sV[2][128 * 72];     // [buf][d][kpos]  (+8 pad)

  const float s_q = fmaxf(scal[1], 1e-8f) / QMAXF;
  const float s_k = fmaxf(scal[2], 1e-8f) / QMAXF;
  const float s_v = fmaxf(scal[3], 1e-8f) / QMAXF;
  const float qkscale = s_q * s_k * 0.08838834764831845f;  // * HD^-0.5
  const float osc = s_v * (1.0f / QMAXF);
  const float NEGINF = -__builtin_inff();

  // staging coords
  const int kr_ = tid >> 2, ks_ = tid & 3;          // K: kpos-row, 32-half seg
  const int vr_ = tid >> 1, vh_ = tid & 1;          // V: d-row, 32-half half
  const _Float16* gK0 = Kh + (size_t)kr_ * 1024 + kvh * 128 + ks_ * 32;
  const _Float16* gV0 = Vt + (size_t)kvh * HEADD * S_LEN + (size_t)vr_ * S_LEN + vh_ * 32;

  for (int hf = 0; hf < 2; hf++){
    const int qb = hf ? 31 - (int)blockIdx.x : (int)blockIdx.x;
    const int nk = qb + 1;
    const int qrow = qb * 64 + wid * 16 + l16;       // this lane's q row
    const int qloc = wid * 16 + l16;                 // q within tile (for diag mask)

    // Q B-frags: B[n=q][k=d], lane n=l16, k=quad*8+j
    half8 qf[2][4];
#pragma unroll
    for (int hh = 0; hh < 2; hh++)
#pragma unroll
      for (int kk = 0; kk < 4; kk++)
        qf[hh][kk] = *(const half8*)(Qh + (size_t)qrow * 4096 + (h0 + hh) * 128 + kk * 32 + quad * 8);

    float mh[2] = { NEGINF, NEGINF };
    float lh[2] = { 0.f, 0.f };

    // ---- pass 1: exact row max + denominator ----
    uint4 kpre[4];
    {
      const uint4* g = (const uint4*)gK0;
#pragma unroll
      for (int j = 0; j < 4; j++) kpre[j] = g[j];
    }
    __syncthreads();   // previous pass/half done with LDS
    for (int kt = 0; kt < nk; ++kt){
      const int b = kt & 1;
      { uint4* d = (uint4*)(sK[b] + kr_ * 136 + ks_ * 32);
#pragma unroll
        for (int j = 0; j < 4; j++) d[j] = kpre[j]; }
      __syncthreads();
      if (kt + 1 < nk){
        const uint4* g = (const uint4*)(gK0 + (size_t)(kt + 1) * 65536);
#pragma unroll
        for (int j = 0; j < 4; j++) kpre[j] = g[j];
      }
      const bool diag = (kt == qb);
      floatx4 c0[4], c1[4];
#pragma unroll
      for (int mt = 0; mt < 4; mt++){
        c0[mt] = (floatx4){0.f,0.f,0.f,0.f}; c1[mt] = (floatx4){0.f,0.f,0.f,0.f};
#pragma unroll
        for (int kk = 0; kk < 4; kk++){
          half8 a = *(const half8*)(sK[b] + (mt * 16 + l16) * 136 + kk * 32 + quad * 8);
          c0[mt] = __builtin_amdgcn_mfma_f32_16x16x32_f16(a, qf[0][kk], c0[mt], 0, 0, 0);
          c1[mt] = __builtin_amdgcn_mfma_f32_16x16x32_f16(a, qf[1][kk], c1[mt], 0, 0, 0);
        }
      }
      // scale + mask into c, then per-head softmax state update
#pragma unroll
      for (int mt = 0; mt < 4; mt++)
#pragma unroll
        for (int rr = 0; rr < 4; rr++){
          bool ok = !diag || (mt * 16 + quad * 4 + rr <= qloc);
          c0[mt][rr] = ok ? c0[mt][rr] * qkscale : NEGINF;
          c1[mt][rr] = ok ? c1[mt][rr] * qkscale : NEGINF;
        }
#pragma unroll
      for (int hh = 0; hh < 2; hh++){
        floatx4* c = hh ? c1 : c0;
        float vmax = NEGINF;
#pragma unroll
        for (int mt = 0; mt < 4; mt++)
#pragma unroll
          for (int rr = 0; rr < 4; rr++) vmax = fmaxf(vmax, c[mt][rr]);
        vmax = fmaxf(vmax, __shfl_xor(vmax, 16));
        vmax = fmaxf(vmax, __shfl_xor(vmax, 32));
        float mnew = fmaxf(mh[hh], vmax);
        float sum = 0.f;
#pragma unroll
        for (int mt = 0; mt < 4; mt++)
#pragma unroll
          for (int rr = 0; rr < 4; rr++) sum += __expf(c[mt][rr] - mnew);
        sum += __shfl_xor(sum, 16);
        sum += __shfl_xor(sum, 32);
        lh[hh] = lh[hh] * __expf(mh[hh] - mnew) + sum;
        mh[hh] = mnew;
      }
    }
    float il[2] = { QMAXF * __builtin_amdgcn_rcpf(lh[0]),
                    QMAXF * __builtin_amdgcn_rcpf(lh[1]) };

    // ---- pass 2: recompute, quantize probs in-register, PV ----
    floatx4 accO[2][8] = {};
    uint4 kpre2[4], vpre2[4];
    {
      const uint4* g = (const uint4*)gK0;
      const uint4* v = (const uint4*)gV0;
#pragma unroll
      for (int j = 0; j < 4; j++){ kpre2[j] = g[j]; vpre2[j] = v[j]; }
    }
    __syncthreads();   // pass-1 reads done
    for (int kt = 0; kt < nk; ++kt){
      const int b = kt & 1;
      { uint4* d = (uint4*)(sK[b] + kr_ * 136 + ks_ * 32);
        uint4* e = (uint4*)(sV[b] + vr_ * 72 + vh_ * 32);
#pragma unroll
        for (int j = 0; j < 4; j++){ d[j] = kpre2[j]; e[j] = vpre2[j]; } }
      __syncthreads();
      if (kt + 1 < nk){
        const uint4* g = (const uint4*)(gK0 + (size_t)(kt + 1) * 65536);
        const uint4* v = (const uint4*)(gV0 + (kt + 1) * 64);
#pragma unroll
        for (int j = 0; j < 4; j++){ kpre2[j] = g[j]; vpre2[j] = v[j]; }
      }
      const bool diag = (kt == qb);
      floatx4 c0[4], c1[4];
#pragma unroll
      for (int mt = 0; mt < 4; mt++){
        c0[mt] = (floatx4){0.f,0.f,0.f,0.f}; c1[mt] = (floatx4){0.f,0.f,0.f,0.f};
#pragma unroll
        for (int kk = 0; kk < 4; kk++){
          half8 a = *(const half8*)(sK[b] + (mt * 16 + l16) * 136 + kk * 32 + quad * 8);
          c0[mt] = __builtin_amdgcn_mfma_f32_16x16x32_f16(a, qf[0][kk], c0[mt], 0, 0, 0);
          c1[mt] = __builtin_amdgcn_mfma_f32_16x16x32_f16(a, qf[1][kk], c1[mt], 0, 0, 0);
        }
      }
      // quantized probs -> PV B-frags (half4), no LDS round-trip
      half4 pk[2][4];
#pragma unroll
      for (int hh = 0; hh < 2; hh++){
        floatx4* c = hh ? c1 : c0;
#pragma unroll
        for (int mt = 0; mt < 4; mt++){
          half4 p;
#pragma unroll
          for (int rr = 0; rr < 4; rr++){
            bool ok = !diag || (mt * 16 + quad * 4 + rr <= qloc);
            float s = ok ? c[mt][rr] * qkscale : NEGINF;
            float pq = fminf(rintf(__expf(s - mh[hh]) * il[hh]), 127.f);
            p[rr] = (_Float16)pq;
          }
          pk[hh][mt] = p;
        }
      }
      // PV: O^T[d][q] += V^T[d][k] . P^T[k][q]  (A = V-frag b64, B = pk)
#pragma unroll
      for (int mt = 0; mt < 4; mt++)
#pragma unroll
        for (int dt = 0; dt < 8; dt++){
          half4 va = *(const half4*)(sV[b] + (dt * 16 + l16) * 72 + mt * 16 + quad * 4);
          accO[0][dt] = __builtin_amdgcn_mfma_f32_16x16x16f16(va, pk[0][mt], accO[0][dt], 0, 0, 0);
          accO[1][dt] = __builtin_amdgcn_mfma_f32_16x16x16f16(va, pk[1][mt], accO[1][dt], 0, 0, 0);
        }
    }

    // epilogue: C-layout col=q(l16), row=d(quad*4+rr) -> coalesced float4 rows
#pragma unroll
    for (int hh = 0; hh < 2; hh++)
#pragma unroll
      for (int dt = 0; dt < 8; dt++){
        float4 o = { accO[hh][dt][0] * osc, accO[hh][dt][1] * osc,
                     accO[hh][dt][2] * osc, accO[hh][dt][3] * osc };
        *(float4*)(AO + (size_t)qrow * 4096 + (h0 + hh) * 128 + dt * 16 + quad * 4) = o;
      }
  }
}

// ---------------- launch ----------------
extern "C" void kernel_launch(void* const* d_in, const int* in_sizes, int n_in,
                              void* d_out, int out_size, void* d_ws, size_t ws_size,
                              hipStream_t stream)
{
  const float* hidden = (const float*)d_in[0];
  // d_in[1] attention_mask: deterministic causal -> computed analytically
  const float* cosb = (const float*)d_in[2];
  const float* sinb = (const float*)d_in[3];
  const float* wq = (const float*)d_in[4];
  const float* wk = (const float*)d_in[5];
  const float* wv = (const float*)d_in[6];
  const float* wo = (const float*)d_in[7];
  float* out = (float*)d_out;

  char* ws = (char*)d_ws;
  size_t off = 0;
  auto alloc = [&](size_t bytes){ size_t o = off; off += (bytes + 255) & ~(size_t)255; return o; };
  float*    scal  = (float*)   (ws + alloc(64));                       // amax: x,q,k,v,ao
  float*    wsc   = (float*)   (ws + alloc(10240 * 4));                // per-row weight scales
  float*    qpart = (float*)   (ws + alloc(ROPE_BLOCKS * 4));
  float*    kpart = (float*)   (ws + alloc(ROPE_BLOCKS * 4));
  _Float16* Wall  = (_Float16*)(ws + alloc((size_t)6144 * 4096 * 2));  // wq|wk|wv int-f16
  _Float16* Wo    = (_Float16*)(ws + alloc((size_t)4096 * 4096 * 2));
  _Float16* Xq    = (_Float16*)(ws + alloc((size_t)2048 * 4096 * 2));
  float*    Y     = (float*)   (ws + alloc((size_t)2048 * 6144 * 4));  // qkv proj fp32
  // aliases (lifetimes disjoint)
  _Float16* Qh  = Xq;
  _Float16* Kh  = Wall;
  _Float16* Vt  = Wall + (size_t)2048 * 1024;
  float*    AO  = Y;
  _Float16* AOq = (_Float16*)((char*)Y + (size_t)2048 * 4096 * 4);

  unsigned* su = (unsigned*)scal;

  k_init<<<dim3(1), dim3(64), 0, stream>>>(scal);
  k_quant_w<<<dim3(10240), dim3(256), 0, stream>>>(wq, wk, wv, wo, Wall, Wo, wsc);
  k_amax<<<dim3(256), dim3(256), 0, stream>>>(hidden, (size_t)(2048 * 4096 / 4), su + 0);
  k_quant<<<dim3(2048), dim3(256), 0, stream>>>(hidden, Xq, (size_t)(2048 * 4096 / 4), scal + 0);
  k_gemm_nt<<<dim3(16, 48), dim3(256), 0, stream>>>(Xq, Wall, scal + 0, wsc, Y, 2048, 6144, 4096);
  k_rope<<<dim3(ROPE_BLOCKS), dim3(256), 0, stream>>>(Y, cosb, sinb, qpart, kpart);
  k_reduce_qk<<<dim3(2), dim3(256), 0, stream>>>(qpart, kpart, scal);
  k_amax_v<<<dim3(256), dim3(256), 0, stream>>>(Y, su + 3);
  k_quant_qk<<<dim3(10240), dim3(256), 0, stream>>>(Y, Qh, Kh, scal);
  k_quant_vt<<<dim3(32, 8, 2), dim3(256), 0, stream>>>(Y, Vt, scal);
  k_attn<<<dim3(16, 16), dim3(256), 0, stream>>>(Qh, Kh, Vt, scal, AO);
  k_amax<<<dim3(256), dim3(256), 0, stream>>>(AO, (size_t)(2048 * 4096 / 4), su + 4);
  k_quant<<<dim3(2048), dim3(256), 0, stream>>>(AO, AOq, (size_t)(2048 * 4096 / 4), scal + 4);
  k_gemm_nt<<<dim3(16, 32), dim3(256), 0, stream>>>(AOq, Wo, scal + 4, wsc + 6144, out, 2048, 4096, 4096);
}